// Round 9
// baseline (48.014 us; speedup 1.0000x reference)
//
#include <hip/hip_runtime.h>

#define HW_ 409600      // 640*640
#define NPIX 3276800    // 8*640*640
#define NB 4096         // histogram bins (fallback top-k path)
#define NGCN 4096
#define NBLK 1600       // k_main grid: 1600*256 threads * 2 groups * 4 px = NPIX exactly
#define HBLK 64         // k_hist grid (fallback, normally early-exits)

typedef float vf4 __attribute__((ext_vector_type(4)));
typedef int vi4 __attribute__((ext_vector_type(4)));

struct Ws {
  double sums[8];          // 0: pos-sum (for fallback fin2)
  unsigned int cnts[8];    // 0:n_pos 3:flag 4:k 5:maxneg_bits 6:done2
  unsigned int hcnt[NB];
  float hsum[NB];
  float pf[NBLK][8];       // per-block partials: pos,neg,tcl,sin,cos,rad,gcn,maxneg
  unsigned int pc[NBLK][4];// per-block counts: n_pos,n_neg,n_tcl
};

__device__ __forceinline__ float ce2(float a0, float a1, int label) {
  float mx = fmaxf(a0, a1);
  float mn = fminf(a0, a1);
  float lse = mx + __logf(1.0f + __expf(mn - mx));
  return lse - (label ? a1 : a0);
}

struct Acc {
  float s_pos, s_neg, s_tcl, s_sin, s_cos, s_rad;
  unsigned int c_pos, c_neg, c_tcl;
  float mx_neg;
};

__device__ __forceinline__ void consume4(
    Acc& a, vf4 v0, vf4 v1, vf4 v2, vf4 v3, vf4 v4, vf4 v5, vf4 v6, vf4 v7,
    vi4 wtm, vi4 wtr, vi4 tca, vi4 tcb, vf4 ra, vf4 rb, vf4 vs, vf4 vc) {
  float a0[4] = {v0.x, v0.y, v0.z, v0.w};
  float a1[4] = {v1.x, v1.y, v1.z, v1.w};
  float a2[4] = {v2.x, v2.y, v2.z, v2.w};
  float a3[4] = {v3.x, v3.y, v3.z, v3.w};
  float a4[4] = {v4.x, v4.y, v4.z, v4.w};
  float a5[4] = {v5.x, v5.y, v5.z, v5.w};
  float a6[4] = {v6.x, v6.y, v6.z, v6.w};
  float a7[4] = {v7.x, v7.y, v7.z, v7.w};
  int tmj[4] = {wtm.x, wtm.y, wtm.z, wtm.w};
  int trj[4] = {wtr.x, wtr.y, wtr.z, wtr.w};
  int tcj[4] = {tca.x, tca.z, tcb.x, tcb.z};
  float topt[4] = {ra.x, ra.z, rb.x, rb.z};
  float bott[4] = {ra.y, ra.w, rb.y, rb.w};
  float sint[4] = {vs.x, vs.y, vs.z, vs.w};
  float cost[4] = {vc.x, vc.y, vc.z, vc.w};
#pragma unroll
  for (int j = 0; j < 4; ++j) {
    bool pos = (trj[j] * tmj[j]) > 0;
    bool neg = ((1 - trj[j]) * tmj[j]) > 0;
    float ltr = ce2(a0[j], a1[j], trj[j]);
    if (pos) { a.s_pos += ltr; a.c_pos++; }
    if (neg) { a.s_neg += ltr; a.c_neg++; a.mx_neg = fmaxf(a.mx_neg, ltr); }
    float ltc = ce2(a2[j], a3[j], tcj[j]);
    if (pos) a.s_tcl += ltc;
    bool tc = tcj[j] > 0;
    float sp = a4[j], cp = a5[j];
    float sc = __builtin_amdgcn_rsqf(sp * sp + cp * cp + 1e-4f);
    sp *= sc; cp *= sc;
    float dsin = fabsf(sp - sint[j]);
    float dcos = fabsf(cp - cost[j]);
    const float inv9 = 1.f / 9.f;
    float slsin = dsin < inv9 ? 4.5f * dsin * dsin : dsin - 0.5f * inv9;
    float slcos = dcos < inv9 ? 4.5f * dcos * dcos : dcos - 0.5f * inv9;
    float dtop = fabsf(a6[j] * __builtin_amdgcn_rcpf(topt[j] + 0.01f) - 1.f);
    float dbot = fabsf(a7[j] * __builtin_amdgcn_rcpf(bott[j] + 0.01f) - 1.f);
    float sltop = dtop < 1.f ? 0.5f * dtop * dtop : dtop - 0.5f;
    float slbot = dbot < 1.f ? 0.5f * dbot * dbot : dbot - 0.5f;
    if (tc) { a.s_sin += slsin; a.s_cos += slcos; a.s_rad += sltop + slbot; a.c_tcl++; }
  }
}

__global__ __launch_bounds__(256, 2) void k_main(
    const float* __restrict__ inp,
    const float* __restrict__ gcn_pred,
    const int* __restrict__ gcn_lab,
    const int* __restrict__ tmm,
    const int* __restrict__ trm,
    const int* __restrict__ tclm,
    const float* __restrict__ radm,
    const float* __restrict__ sinm,
    const float* __restrict__ cosm,
    Ws* __restrict__ ws) {
  Acc a = {0.f, 0.f, 0.f, 0.f, 0.f, 0.f, 0u, 0u, 0u, 0.f};
  float s_gcn = 0.f;

  int tid = threadIdx.x + blockIdx.x * blockDim.x;  // 0..409599

  if (tid < NGCN) {
    s_gcn = ce2(gcn_pred[2 * tid], gcn_pred[2 * tid + 1], gcn_lab[tid]);
  }

  // Two 4-pixel groups per thread; group B is exactly 4 batches ahead (same q).
  // All 32 stream loads issued stream-major before any consumption.
  {
    int p = tid * 4;
    int b = p / HW_;
    int q = p - b * HW_;
    const float* baseA = inp + (size_t)b * 8 * HW_ + q;
    const float* baseB = baseA + (size_t)4 * 8 * HW_;  // b+4, same q
    int pB = p + NPIX / 2;

    vf4 A0 = *(const vf4*)(baseA);
    vf4 B0 = *(const vf4*)(baseB);
    vf4 A1 = *(const vf4*)(baseA + HW_);
    vf4 B1 = *(const vf4*)(baseB + HW_);
    vf4 A2 = *(const vf4*)(baseA + 2 * HW_);
    vf4 B2 = *(const vf4*)(baseB + 2 * HW_);
    vf4 A3 = *(const vf4*)(baseA + 3 * HW_);
    vf4 B3 = *(const vf4*)(baseB + 3 * HW_);
    vf4 A4 = *(const vf4*)(baseA + 4 * HW_);
    vf4 B4 = *(const vf4*)(baseB + 4 * HW_);
    vf4 A5 = *(const vf4*)(baseA + 5 * HW_);
    vf4 B5 = *(const vf4*)(baseB + 5 * HW_);
    vf4 A6 = *(const vf4*)(baseA + 6 * HW_);
    vf4 B6 = *(const vf4*)(baseB + 6 * HW_);
    vf4 A7 = *(const vf4*)(baseA + 7 * HW_);
    vf4 B7 = *(const vf4*)(baseB + 7 * HW_);
    vi4 wtmA = *(const vi4*)(tmm + p);
    vi4 wtmB = *(const vi4*)(tmm + pB);
    vi4 wtrA = *(const vi4*)(trm + p);
    vi4 wtrB = *(const vi4*)(trm + pB);
    vi4 tcaA = *(const vi4*)(tclm + 2 * p);
    vi4 tcbA = *(const vi4*)(tclm + 2 * p + 4);
    vi4 tcaB = *(const vi4*)(tclm + 2 * pB);
    vi4 tcbB = *(const vi4*)(tclm + 2 * pB + 4);
    vf4 raA = *(const vf4*)(radm + 2 * p);
    vf4 rbA = *(const vf4*)(radm + 2 * p + 4);
    vf4 raB = *(const vf4*)(radm + 2 * pB);
    vf4 rbB = *(const vf4*)(radm + 2 * pB + 4);
    vf4 vsA = *(const vf4*)(sinm + p);
    vf4 vsB = *(const vf4*)(sinm + pB);
    vf4 vcA = *(const vf4*)(cosm + p);
    vf4 vcB = *(const vf4*)(cosm + pB);

    consume4(a, A0, A1, A2, A3, A4, A5, A6, A7, wtmA, wtrA, tcaA, tcbA, raA, rbA, vsA, vcA);
    consume4(a, B0, B1, B2, B3, B4, B5, B6, B7, wtmB, wtrB, tcaB, tcbB, raB, rbB, vsB, vcB);
  }

  // wave (64-lane) shuffle reduce
#pragma unroll
  for (int off = 32; off > 0; off >>= 1) {
    a.s_pos += __shfl_down(a.s_pos, off);
    a.s_neg += __shfl_down(a.s_neg, off);
    a.s_tcl += __shfl_down(a.s_tcl, off);
    a.s_sin += __shfl_down(a.s_sin, off);
    a.s_cos += __shfl_down(a.s_cos, off);
    a.s_rad += __shfl_down(a.s_rad, off);
    s_gcn   += __shfl_down(s_gcn, off);
    a.c_pos += __shfl_down(a.c_pos, off);
    a.c_neg += __shfl_down(a.c_neg, off);
    a.c_tcl += __shfl_down(a.c_tcl, off);
    a.mx_neg = fmaxf(a.mx_neg, __shfl_down(a.mx_neg, off));
  }
  __shared__ float shf[4][8];
  __shared__ unsigned int shc[4][3];
  int wv = threadIdx.x >> 6, ln = threadIdx.x & 63;
  if (ln == 0) {
    shf[wv][0] = a.s_pos; shf[wv][1] = a.s_neg; shf[wv][2] = a.s_tcl; shf[wv][3] = a.s_sin;
    shf[wv][4] = a.s_cos; shf[wv][5] = a.s_rad; shf[wv][6] = s_gcn;  shf[wv][7] = a.mx_neg;
    shc[wv][0] = a.c_pos; shc[wv][1] = a.c_neg; shc[wv][2] = a.c_tcl;
  }
  __syncthreads();
  if (threadIdx.x == 0) {
    float f0 = 0, f1 = 0, f2 = 0, f3 = 0, f4 = 0, f5 = 0, f6 = 0, f7 = 0;
    unsigned int u0 = 0, u1 = 0, u2 = 0;
#pragma unroll
    for (int w = 0; w < 4; ++w) {
      f0 += shf[w][0]; f1 += shf[w][1]; f2 += shf[w][2]; f3 += shf[w][3];
      f4 += shf[w][4]; f5 += shf[w][5]; f6 += shf[w][6];
      f7 = fmaxf(f7, shf[w][7]);
      u0 += shc[w][0]; u1 += shc[w][1]; u2 += shc[w][2];
    }
    ws->pf[blockIdx.x][0] = f0; ws->pf[blockIdx.x][1] = f1;
    ws->pf[blockIdx.x][2] = f2; ws->pf[blockIdx.x][3] = f3;
    ws->pf[blockIdx.x][4] = f4; ws->pf[blockIdx.x][5] = f5;
    ws->pf[blockIdx.x][6] = f6; ws->pf[blockIdx.x][7] = f7;
    ws->pc[blockIdx.x][0] = u0; ws->pc[blockIdx.x][1] = u1; ws->pc[blockIdx.x][2] = u2;
  }
}

// Fold per-block partials + finalize; also zero histogram + done2 for k_hist.
__global__ __launch_bounds__(1024) void k_reduce(Ws* __restrict__ ws, float* __restrict__ out) {
  int t = threadIdx.x;
#pragma unroll
  for (int i = t; i < NB; i += 1024) { ws->hcnt[i] = 0u; ws->hsum[i] = 0.f; }

  float f[8] = {0, 0, 0, 0, 0, 0, 0, 0};
  unsigned int u[3] = {0, 0, 0};
#pragma unroll
  for (int rep = 0; rep < (NBLK + 1023) / 1024; ++rep) {
    int s = t + rep * 1024;
    if (s < NBLK) {
#pragma unroll
      for (int i = 0; i < 7; ++i) f[i] += ws->pf[s][i];
      f[7] = fmaxf(f[7], ws->pf[s][7]);
#pragma unroll
      for (int i = 0; i < 3; ++i) u[i] += ws->pc[s][i];
    }
  }
#pragma unroll
  for (int off = 32; off > 0; off >>= 1) {
#pragma unroll
    for (int i = 0; i < 7; ++i) f[i] += __shfl_down(f[i], off);
    f[7] = fmaxf(f[7], __shfl_down(f[7], off));
#pragma unroll
    for (int i = 0; i < 3; ++i) u[i] += __shfl_down(u[i], off);
  }
  __shared__ float shf[16][8];
  __shared__ unsigned int shc[16][3];
  int wv = t >> 6, ln = t & 63;
  if (ln == 0) {
#pragma unroll
    for (int i = 0; i < 8; ++i) shf[wv][i] = f[i];
#pragma unroll
    for (int i = 0; i < 3; ++i) shc[wv][i] = u[i];
  }
  __syncthreads();
  if (t == 0) {
    double d[7] = {0, 0, 0, 0, 0, 0, 0};
    float mx = 0.f;
    unsigned int np = 0, nnt = 0, ntc = 0;
#pragma unroll
    for (int w = 0; w < 16; ++w) {
#pragma unroll
      for (int i = 0; i < 7; ++i) d[i] += (double)shf[w][i];
      mx = fmaxf(mx, shf[w][7]);
      np += shc[w][0]; nnt += shc[w][1]; ntc += shc[w][2];
    }
    ws->sums[0] = d[0];
    ws->cnts[0] = np;
    ws->cnts[5] = __float_as_uint(mx);
    ws->cnts[6] = 0u;  // done2 for fused fallback finalize
    out[1] = np > 0 ? (float)(d[2] / (double)np) : 0.f;
    out[2] = ntc > 0 ? (float)(d[3] / (double)ntc) : 0.f;
    out[3] = ntc > 0 ? (float)(d[4] / (double)ntc) : 0.f;
    out[4] = ntc > 0 ? (float)(d[5] / (double)ntc) : 0.f;
    out[5] = (float)(d[6] / (double)NGCN);
    long long nneg;
    if (np > 0) {
      long long cap = (long long)(int)(3.0f * (float)np);  // matches .astype(int32)
      nneg = (long long)nnt < cap ? (long long)nnt : cap;
    } else {
      nneg = (long long)nnt < 100 ? (long long)nnt : 100;
    }
    if (nneg >= (long long)nnt) {
      out[0] = (float)((d[0] + d[1]) / ((double)np + (double)nneg));
      ws->cnts[3] = 0u;
    } else {
      ws->cnts[3] = 1u;
      ws->cnts[4] = (unsigned int)nneg;
    }
  }
}

// Fallback: histogram over negative losses + fused top-k finalize (normally early-exits).
__global__ __launch_bounds__(256) void k_hist(
    const float* __restrict__ inp,
    const int* __restrict__ tmm,
    const int* __restrict__ trm,
    Ws* __restrict__ ws,
    float* __restrict__ out) {
  if (ws->cnts[3] == 0u) return;  // top-k degenerated to full sum; nothing to do
  __shared__ unsigned int lc[NB];
  __shared__ float lsum[NB];
  for (int i = threadIdx.x; i < NB; i += blockDim.x) { lc[i] = 0u; lsum[i] = 0.f; }
  __syncthreads();
  float maxneg = __uint_as_float(ws->cnts[5]);
  float invmax = maxneg > 0.f ? (float)NB / maxneg : 0.f;
  int tid = threadIdx.x + blockIdx.x * blockDim.x;
  int nth = blockDim.x * gridDim.x;
  for (int p = tid; p < NPIX; p += nth) {
    int tmj = tmm[p], trj = trm[p];
    if (((1 - trj) * tmj) > 0) {
      int b = p / HW_;
      int q = p - b * HW_;
      const float* base = inp + (size_t)b * 8 * HW_ + q;
      float ltr = ce2(base[0], base[HW_], trj);
      int bin = (int)(ltr * invmax);
      bin = bin < NB - 1 ? bin : NB - 1;
      bin = bin > 0 ? bin : 0;
      atomicAdd(&lc[bin], 1u);
      atomicAdd(&lsum[bin], ltr);
    }
  }
  __syncthreads();
  for (int i = threadIdx.x; i < NB; i += blockDim.x) {
    if (lc[i]) {
      atomicAdd(&ws->hcnt[i], lc[i]);
      atomicAdd(&ws->hsum[i], lsum[i]);
    }
  }
  // last-block finalize (fallback path only — fences never execute in the common case)
  __shared__ unsigned int last2;
  __threadfence();
  __syncthreads();
  if (threadIdx.x == 0) {
    unsigned int old = atomicAdd(&ws->cnts[6], 1u);
    last2 = (old == HBLK - 1) ? 1u : 0u;
  }
  __syncthreads();
  if (last2 && threadIdx.x == 0) {
    __threadfence();
    unsigned int k = ws->cnts[4];
    double acc = 0.0;
    unsigned int cum = 0;
    for (int b = NB - 1; b >= 0 && cum < k; --b) {
      unsigned int c = ws->hcnt[b];
      if (!c) continue;
      float s = ws->hsum[b];
      if (cum + c <= k) {
        acc += (double)s;
        cum += c;
      } else {
        unsigned int r = k - cum;
        acc += (double)r * ((double)s / (double)c);
        cum = k;
      }
    }
    unsigned int np = ws->cnts[0];
    double spos = ws->sums[0];
    out[0] = (float)((spos + acc) / ((double)np + (double)k));
  }
}

extern "C" void kernel_launch(void* const* d_in, const int* in_sizes, int n_in,
                              void* d_out, int out_size, void* d_ws, size_t ws_size,
                              hipStream_t stream) {
  (void)in_sizes; (void)n_in; (void)out_size; (void)ws_size;
  const float* inp = (const float*)d_in[0];
  const float* gcn_pred = (const float*)d_in[1];
  const int* gcn_lab = (const int*)d_in[2];
  const int* tmm = (const int*)d_in[3];
  const int* trm = (const int*)d_in[4];
  const int* tclm = (const int*)d_in[5];
  const float* radm = (const float*)d_in[6];
  const float* sinm = (const float*)d_in[7];
  const float* cosm = (const float*)d_in[8];
  float* out = (float*)d_out;
  Ws* ws = (Ws*)d_ws;

  k_main<<<NBLK, 256, 0, stream>>>(inp, gcn_pred, gcn_lab, tmm, trm, tclm, radm, sinm, cosm, ws);
  k_reduce<<<1, 1024, 0, stream>>>(ws, out);
  k_hist<<<HBLK, 256, 0, stream>>>(inp, tmm, trm, ws, out);
}

// Round 10
// 45.760 us; speedup vs baseline: 1.0492x; 1.0492x over previous
//
#include <hip/hip_runtime.h>

#define HW_ 409600      // 640*640
#define NPIX 3276800    // 8*640*640
#define NB 4096         // histogram bins (fallback top-k path)
#define NGCN 4096
#define NBLK 3200       // k_main grid: 3200*256 threads * 4 px = NPIX exactly
#define HBLK 64         // k_hist grid (fallback, normally early-exits)

typedef float vf4 __attribute__((ext_vector_type(4)));
typedef int vi4 __attribute__((ext_vector_type(4)));

struct Ws {
  double sums[8];          // 0: pos-sum (for fallback fin2)
  unsigned int cnts[8];    // 0:n_pos 3:flag 4:k 5:maxneg_bits 6:done2
  unsigned int hcnt[NB];
  float hsum[NB];
  float pf[NBLK][8];       // per-block partials: pos,neg,tcl,sin,cos,rad,gcn,maxneg
  unsigned int pc[NBLK][4];// per-block counts: n_pos,n_neg,n_tcl
};

__device__ __forceinline__ float ce2(float a0, float a1, int label) {
  float mx = fmaxf(a0, a1);
  float mn = fminf(a0, a1);
  float lse = mx + __logf(1.0f + __expf(mn - mx));
  return lse - (label ? a1 : a0);
}

__global__ __launch_bounds__(256, 2) void k_main(
    const float* __restrict__ inp,
    const float* __restrict__ gcn_pred,
    const int* __restrict__ gcn_lab,
    const int* __restrict__ tmm,
    const int* __restrict__ trm,
    const int* __restrict__ tclm,
    const float* __restrict__ radm,
    const float* __restrict__ sinm,
    const float* __restrict__ cosm,
    Ws* __restrict__ ws) {
  float s_pos = 0.f, s_neg = 0.f, s_tcl = 0.f, s_sin = 0.f, s_cos = 0.f, s_rad = 0.f, s_gcn = 0.f;
  unsigned int c_pos = 0, c_neg = 0, c_tcl = 0;
  float mx_neg = 0.f;

  int tid = threadIdx.x + blockIdx.x * blockDim.x;  // 0..819199, exactly one group each

  if (tid < NGCN) {
    s_gcn = ce2(gcn_pred[2 * tid], gcn_pred[2 * tid + 1], gcn_lab[tid]);
  }

  {
    int p = tid * 4;
    int b = p / HW_;
    int q = p - b * HW_;
    const float* base = inp + (size_t)b * 8 * HW_ + q;
    vf4 v0 = *(const vf4*)(base);
    vf4 v1 = *(const vf4*)(base + HW_);
    vf4 v2 = *(const vf4*)(base + 2 * HW_);
    vf4 v3 = *(const vf4*)(base + 3 * HW_);
    vf4 v4 = *(const vf4*)(base + 4 * HW_);
    vf4 v5 = *(const vf4*)(base + 5 * HW_);
    vf4 v6 = *(const vf4*)(base + 6 * HW_);
    vf4 v7 = *(const vf4*)(base + 7 * HW_);
    vi4 wtm = *(const vi4*)(tmm + p);
    vi4 wtr = *(const vi4*)(trm + p);
    vi4 tca = *(const vi4*)(tclm + 2 * p);
    vi4 tcb = *(const vi4*)(tclm + 2 * p + 4);
    vf4 ra = *(const vf4*)(radm + 2 * p);
    vf4 rb = *(const vf4*)(radm + 2 * p + 4);
    vf4 vs = *(const vf4*)(sinm + p);
    vf4 vc = *(const vf4*)(cosm + p);

    float a0[4] = {v0.x, v0.y, v0.z, v0.w};
    float a1[4] = {v1.x, v1.y, v1.z, v1.w};
    float a2[4] = {v2.x, v2.y, v2.z, v2.w};
    float a3[4] = {v3.x, v3.y, v3.z, v3.w};
    float a4[4] = {v4.x, v4.y, v4.z, v4.w};
    float a5[4] = {v5.x, v5.y, v5.z, v5.w};
    float a6[4] = {v6.x, v6.y, v6.z, v6.w};
    float a7[4] = {v7.x, v7.y, v7.z, v7.w};
    int tmj[4] = {wtm.x, wtm.y, wtm.z, wtm.w};
    int trj[4] = {wtr.x, wtr.y, wtr.z, wtr.w};
    int tcj[4] = {tca.x, tca.z, tcb.x, tcb.z};
    float topt[4] = {ra.x, ra.z, rb.x, rb.z};
    float bott[4] = {ra.y, ra.w, rb.y, rb.w};
    float sint[4] = {vs.x, vs.y, vs.z, vs.w};
    float cost[4] = {vc.x, vc.y, vc.z, vc.w};

#pragma unroll
    for (int j = 0; j < 4; ++j) {
      bool pos = (trj[j] * tmj[j]) > 0;
      bool neg = ((1 - trj[j]) * tmj[j]) > 0;
      float ltr = ce2(a0[j], a1[j], trj[j]);
      if (pos) { s_pos += ltr; c_pos++; }
      if (neg) { s_neg += ltr; c_neg++; mx_neg = fmaxf(mx_neg, ltr); }
      float ltc = ce2(a2[j], a3[j], tcj[j]);
      if (pos) s_tcl += ltc;
      bool tc = tcj[j] > 0;
      float sp = a4[j], cp = a5[j];
      float sc = __builtin_amdgcn_rsqf(sp * sp + cp * cp + 1e-4f);
      sp *= sc; cp *= sc;
      float dsin = fabsf(sp - sint[j]);
      float dcos = fabsf(cp - cost[j]);
      const float inv9 = 1.f / 9.f;
      float slsin = dsin < inv9 ? 4.5f * dsin * dsin : dsin - 0.5f * inv9;
      float slcos = dcos < inv9 ? 4.5f * dcos * dcos : dcos - 0.5f * inv9;
      float dtop = fabsf(a6[j] * __builtin_amdgcn_rcpf(topt[j] + 0.01f) - 1.f);
      float dbot = fabsf(a7[j] * __builtin_amdgcn_rcpf(bott[j] + 0.01f) - 1.f);
      float sltop = dtop < 1.f ? 0.5f * dtop * dtop : dtop - 0.5f;
      float slbot = dbot < 1.f ? 0.5f * dbot * dbot : dbot - 0.5f;
      if (tc) { s_sin += slsin; s_cos += slcos; s_rad += sltop + slbot; c_tcl++; }
    }
  }

  // wave (64-lane) shuffle reduce
#pragma unroll
  for (int off = 32; off > 0; off >>= 1) {
    s_pos += __shfl_down(s_pos, off);
    s_neg += __shfl_down(s_neg, off);
    s_tcl += __shfl_down(s_tcl, off);
    s_sin += __shfl_down(s_sin, off);
    s_cos += __shfl_down(s_cos, off);
    s_rad += __shfl_down(s_rad, off);
    s_gcn += __shfl_down(s_gcn, off);
    c_pos += __shfl_down(c_pos, off);
    c_neg += __shfl_down(c_neg, off);
    c_tcl += __shfl_down(c_tcl, off);
    mx_neg = fmaxf(mx_neg, __shfl_down(mx_neg, off));
  }
  __shared__ float shf[4][8];
  __shared__ unsigned int shc[4][3];
  int wv = threadIdx.x >> 6, ln = threadIdx.x & 63;
  if (ln == 0) {
    shf[wv][0] = s_pos; shf[wv][1] = s_neg; shf[wv][2] = s_tcl; shf[wv][3] = s_sin;
    shf[wv][4] = s_cos; shf[wv][5] = s_rad; shf[wv][6] = s_gcn; shf[wv][7] = mx_neg;
    shc[wv][0] = c_pos; shc[wv][1] = c_neg; shc[wv][2] = c_tcl;
  }
  __syncthreads();
  if (threadIdx.x == 0) {
    float f0 = 0, f1 = 0, f2 = 0, f3 = 0, f4 = 0, f5 = 0, f6 = 0, f7 = 0;
    unsigned int u0 = 0, u1 = 0, u2 = 0;
#pragma unroll
    for (int w = 0; w < 4; ++w) {
      f0 += shf[w][0]; f1 += shf[w][1]; f2 += shf[w][2]; f3 += shf[w][3];
      f4 += shf[w][4]; f5 += shf[w][5]; f6 += shf[w][6];
      f7 = fmaxf(f7, shf[w][7]);
      u0 += shc[w][0]; u1 += shc[w][1]; u2 += shc[w][2];
    }
    ws->pf[blockIdx.x][0] = f0; ws->pf[blockIdx.x][1] = f1;
    ws->pf[blockIdx.x][2] = f2; ws->pf[blockIdx.x][3] = f3;
    ws->pf[blockIdx.x][4] = f4; ws->pf[blockIdx.x][5] = f5;
    ws->pf[blockIdx.x][6] = f6; ws->pf[blockIdx.x][7] = f7;
    ws->pc[blockIdx.x][0] = u0; ws->pc[blockIdx.x][1] = u1; ws->pc[blockIdx.x][2] = u2;
  }
}

// Fold per-block partials + finalize; also zero histogram + done2 for k_hist.
__global__ __launch_bounds__(1024) void k_reduce(Ws* __restrict__ ws, float* __restrict__ out) {
  int t = threadIdx.x;
#pragma unroll
  for (int i = t; i < NB; i += 1024) { ws->hcnt[i] = 0u; ws->hsum[i] = 0.f; }

  float f[8] = {0, 0, 0, 0, 0, 0, 0, 0};
  unsigned int u[3] = {0, 0, 0};
#pragma unroll
  for (int rep = 0; rep < (NBLK + 1023) / 1024; ++rep) {
    int s = t + rep * 1024;
    if (s < NBLK) {
#pragma unroll
      for (int i = 0; i < 7; ++i) f[i] += ws->pf[s][i];
      f[7] = fmaxf(f[7], ws->pf[s][7]);
#pragma unroll
      for (int i = 0; i < 3; ++i) u[i] += ws->pc[s][i];
    }
  }
#pragma unroll
  for (int off = 32; off > 0; off >>= 1) {
#pragma unroll
    for (int i = 0; i < 7; ++i) f[i] += __shfl_down(f[i], off);
    f[7] = fmaxf(f[7], __shfl_down(f[7], off));
#pragma unroll
    for (int i = 0; i < 3; ++i) u[i] += __shfl_down(u[i], off);
  }
  __shared__ float shf[16][8];
  __shared__ unsigned int shc[16][3];
  int wv = t >> 6, ln = t & 63;
  if (ln == 0) {
#pragma unroll
    for (int i = 0; i < 8; ++i) shf[wv][i] = f[i];
#pragma unroll
    for (int i = 0; i < 3; ++i) shc[wv][i] = u[i];
  }
  __syncthreads();
  if (t == 0) {
    double d[7] = {0, 0, 0, 0, 0, 0, 0};
    float mx = 0.f;
    unsigned int np = 0, nnt = 0, ntc = 0;
#pragma unroll
    for (int w = 0; w < 16; ++w) {
#pragma unroll
      for (int i = 0; i < 7; ++i) d[i] += (double)shf[w][i];
      mx = fmaxf(mx, shf[w][7]);
      np += shc[w][0]; nnt += shc[w][1]; ntc += shc[w][2];
    }
    ws->sums[0] = d[0];
    ws->cnts[0] = np;
    ws->cnts[5] = __float_as_uint(mx);
    ws->cnts[6] = 0u;  // done2 for fused fallback finalize
    out[1] = np > 0 ? (float)(d[2] / (double)np) : 0.f;
    out[2] = ntc > 0 ? (float)(d[3] / (double)ntc) : 0.f;
    out[3] = ntc > 0 ? (float)(d[4] / (double)ntc) : 0.f;
    out[4] = ntc > 0 ? (float)(d[5] / (double)ntc) : 0.f;
    out[5] = (float)(d[6] / (double)NGCN);
    long long nneg;
    if (np > 0) {
      long long cap = (long long)(int)(3.0f * (float)np);  // matches .astype(int32)
      nneg = (long long)nnt < cap ? (long long)nnt : cap;
    } else {
      nneg = (long long)nnt < 100 ? (long long)nnt : 100;
    }
    if (nneg >= (long long)nnt) {
      out[0] = (float)((d[0] + d[1]) / ((double)np + (double)nneg));
      ws->cnts[3] = 0u;
    } else {
      ws->cnts[3] = 1u;
      ws->cnts[4] = (unsigned int)nneg;
    }
  }
}

// Fallback: histogram over negative losses + fused top-k finalize (normally early-exits).
__global__ __launch_bounds__(256) void k_hist(
    const float* __restrict__ inp,
    const int* __restrict__ tmm,
    const int* __restrict__ trm,
    Ws* __restrict__ ws,
    float* __restrict__ out) {
  if (ws->cnts[3] == 0u) return;  // top-k degenerated to full sum; nothing to do
  __shared__ unsigned int lc[NB];
  __shared__ float lsum[NB];
  for (int i = threadIdx.x; i < NB; i += blockDim.x) { lc[i] = 0u; lsum[i] = 0.f; }
  __syncthreads();
  float maxneg = __uint_as_float(ws->cnts[5]);
  float invmax = maxneg > 0.f ? (float)NB / maxneg : 0.f;
  int tid = threadIdx.x + blockIdx.x * blockDim.x;
  int nth = blockDim.x * gridDim.x;
  for (int p = tid; p < NPIX; p += nth) {
    int tmj = tmm[p], trj = trm[p];
    if (((1 - trj) * tmj) > 0) {
      int b = p / HW_;
      int q = p - b * HW_;
      const float* base = inp + (size_t)b * 8 * HW_ + q;
      float ltr = ce2(base[0], base[HW_], trj);
      int bin = (int)(ltr * invmax);
      bin = bin < NB - 1 ? bin : NB - 1;
      bin = bin > 0 ? bin : 0;
      atomicAdd(&lc[bin], 1u);
      atomicAdd(&lsum[bin], ltr);
    }
  }
  __syncthreads();
  for (int i = threadIdx.x; i < NB; i += blockDim.x) {
    if (lc[i]) {
      atomicAdd(&ws->hcnt[i], lc[i]);
      atomicAdd(&ws->hsum[i], lsum[i]);
    }
  }
  // last-block finalize (fallback path only — fences never execute in the common case)
  __shared__ unsigned int last2;
  __threadfence();
  __syncthreads();
  if (threadIdx.x == 0) {
    unsigned int old = atomicAdd(&ws->cnts[6], 1u);
    last2 = (old == HBLK - 1) ? 1u : 0u;
  }
  __syncthreads();
  if (last2 && threadIdx.x == 0) {
    __threadfence();
    unsigned int k = ws->cnts[4];
    double acc = 0.0;
    unsigned int cum = 0;
    for (int b = NB - 1; b >= 0 && cum < k; --b) {
      unsigned int c = ws->hcnt[b];
      if (!c) continue;
      float s = ws->hsum[b];
      if (cum + c <= k) {
        acc += (double)s;
        cum += c;
      } else {
        unsigned int r = k - cum;
        acc += (double)r * ((double)s / (double)c);
        cum = k;
      }
    }
    unsigned int np = ws->cnts[0];
    double spos = ws->sums[0];
    out[0] = (float)((spos + acc) / ((double)np + (double)k));
  }
}

extern "C" void kernel_launch(void* const* d_in, const int* in_sizes, int n_in,
                              void* d_out, int out_size, void* d_ws, size_t ws_size,
                              hipStream_t stream) {
  (void)in_sizes; (void)n_in; (void)out_size; (void)ws_size;
  const float* inp = (const float*)d_in[0];
  const float* gcn_pred = (const float*)d_in[1];
  const int* gcn_lab = (const int*)d_in[2];
  const int* tmm = (const int*)d_in[3];
  const int* trm = (const int*)d_in[4];
  const int* tclm = (const int*)d_in[5];
  const float* radm = (const float*)d_in[6];
  const float* sinm = (const float*)d_in[7];
  const float* cosm = (const float*)d_in[8];
  float* out = (float*)d_out;
  Ws* ws = (Ws*)d_ws;

  k_main<<<NBLK, 256, 0, stream>>>(inp, gcn_pred, gcn_lab, tmm, trm, tclm, radm, sinm, cosm, ws);
  k_reduce<<<1, 1024, 0, stream>>>(ws, out);
  k_hist<<<HBLK, 256, 0, stream>>>(inp, tmm, trm, ws, out);
}